// Round 1
// baseline (27.489 us; speedup 1.0000x reference)
//
#include <hip/hip_runtime.h>

// TBSyntaxParser: per-state feature gather + 2-layer MLP + legal mask.
// B=4096 states, L=128 buffer slots, D=60 feat dim, X=6*D=360, HID=200, OUT=3.
// d_out layout: [out (B*3) | legal (B*3)] concatenated, float32.

#define Bq   4096
#define Lq   128
#define Dq   60
#define XDIM 360
#define HID  200
#define ONUM 3
#define G    8     // states per block
#define NT   256   // threads per block

__global__ __launch_bounds__(NT) void parser_kernel(
    const float* __restrict__ buffer,
    const float* __restrict__ W1,
    const float* __restrict__ b1,
    const float* __restrict__ W2,
    const float* __restrict__ b2,
    const int*   __restrict__ buffer_index,
    const int*   __restrict__ stack_indexes,
    const int*   __restrict__ stack_len,
    float*       __restrict__ out)
{
    __shared__ float4 X4[G][90];        // X[G][360] floats as float4
    __shared__ float  hid[G][201];      // pad 200->201: conflict-free stride-200 reads
    __shared__ int    sRow[G][6];       // gather row per segment
    __shared__ int    sBi[G], sSl[G];

    const int t  = threadIdx.x;
    const int s0 = blockIdx.x * G;      // first state of this block

    // ---- stage indices ----
    if (t < G) {
        int bi = buffer_index[s0 + t];
        sBi[t] = bi;
        sSl[t] = stack_len[s0 + t];
        sRow[t][0] = bi; sRow[t][1] = bi + 1; sRow[t][2] = bi + 2;
    }
    if (t < G * 3) {
        int s = t / 3, c = t % 3;
        sRow[s][3 + c] = stack_indexes[(s0 + s) * 3 + c];
    }
    __syncthreads();

    // ---- stage X: G*6 rows of 60 floats = G*90 float4 (rows are 240B => 16B aligned) ----
    for (int i = t; i < G * 90; i += NT) {
        int s   = i / 90;
        int r   = i % 90;
        int seg = r / 15;     // which of the 6 gathered rows
        int f   = r % 15;     // float4 within the row
        int row = sRow[s][seg];
        const float4* src =
            (const float4*)(buffer + ((size_t)(s0 + s) * Lq + row) * Dq);
        X4[s][seg * 15 + f] = src[f];
    }

    // ---- legal mask (independent of X; overlap with staging) ----
    if (t < G * ONUM) {
        int s = t / ONUM, o = t % ONUM;
        float lg;
        if (o == 0)      lg = (sBi[s] + 3 >= Lq) ? 0.f : 1.f;   // shift
        else if (o == 1) lg = (sSl[s] <= 3)      ? 0.f : 1.f;   // left-arc
        else             lg = (sSl[s] <= 4)      ? 0.f : 1.f;   // right-arc
        out[(size_t)Bq * ONUM + (size_t)(s0 + s) * ONUM + o] = lg;
    }
    __syncthreads();

    // ---- hidden layer: thread j computes hid[j] for all G states ----
    if (t < HID) {
        float acc[G];
        #pragma unroll
        for (int s = 0; s < G; ++s) acc[s] = 0.f;

        for (int kk = 0; kk < XDIM / 4; ++kk) {
            // W1 row-major [360][200]; coalesced across threads
            float w0 = W1[(4 * kk + 0) * HID + t];
            float w1v = W1[(4 * kk + 1) * HID + t];
            float w2v = W1[(4 * kk + 2) * HID + t];
            float w3v = W1[(4 * kk + 3) * HID + t];
            #pragma unroll
            for (int s = 0; s < G; ++s) {
                float4 x = X4[s][kk];        // same-address broadcast, conflict-free
                acc[s] = fmaf(x.x, w0,  acc[s]);
                acc[s] = fmaf(x.y, w1v, acc[s]);
                acc[s] = fmaf(x.z, w2v, acc[s]);
                acc[s] = fmaf(x.w, w3v, acc[s]);
            }
        }
        float bb = b1[t];
        #pragma unroll
        for (int s = 0; s < G; ++s) {
            float h = acc[s] + bb;
            hid[s][t] = h > 0.f ? h : 0.f;
        }
    }
    __syncthreads();

    // ---- output layer: G*3 threads, 200-MAC dot each ----
    if (t < G * ONUM) {
        int s = t / ONUM, o = t % ONUM;
        float a0 = 0.f, a1 = 0.f;
        #pragma unroll 4
        for (int j = 0; j < HID; j += 2) {   // 2 chains to shorten dep latency
            a0 = fmaf(hid[s][j],     W2[(j)     * ONUM + o], a0);
            a1 = fmaf(hid[s][j + 1], W2[(j + 1) * ONUM + o], a1);
        }
        out[(size_t)(s0 + s) * ONUM + o] = a0 + a1 + b2[o];
    }
}

extern "C" void kernel_launch(void* const* d_in, const int* in_sizes, int n_in,
                              void* d_out, int out_size, void* d_ws, size_t ws_size,
                              hipStream_t stream) {
    const float* buffer        = (const float*)d_in[0];
    const float* W1            = (const float*)d_in[1];
    const float* b1            = (const float*)d_in[2];
    const float* W2            = (const float*)d_in[3];
    const float* b2            = (const float*)d_in[4];
    const int*   buffer_index  = (const int*)d_in[5];
    const int*   stack_indexes = (const int*)d_in[6];
    const int*   stack_len     = (const int*)d_in[7];
    float*       out           = (float*)d_out;

    parser_kernel<<<Bq / G, NT, 0, stream>>>(
        buffer, W1, b1, W2, b2, buffer_index, stack_indexes, stack_len, out);
}

// Round 2
// 22.276 us; speedup vs baseline: 1.2340x; 1.2340x over previous
//
#include <hip/hip_runtime.h>

// TBSyntaxParser via bf16 MFMA.
// B=4096, L=128, D=60, X=6*60=360(k, pad 384), HID=200(n, pad 208), OUT=3.
// d_out = [out (B*3) | legal (B*3)] f32.
//
// prep_w1: packs W1 into per-lane B-fragment order (bf16) in d_ws.
// parser_mfma: gathers X rows -> bf16 A-fragments in LDS -> MFMA layer-1 ->
//              ReLU+bias -> LDS hid -> VALU layer-2 -> out + legal mask.

#define Bq    4096
#define Lq    128
#define Dq    60
#define HIDq  200
#define ONUM  3
#define KTN   12      // k-tiles (384/32)
#define NTN   13      // n-tiles (208/16)
#define MB    16      // states per block
#define NTHR  256

typedef short  bf16x8 __attribute__((ext_vector_type(8)));
typedef float  f32x4  __attribute__((ext_vector_type(4)));

__device__ __forceinline__ unsigned short f2bf(float f) {
    union { float f; unsigned int u; } v; v.f = f;
    unsigned int u = v.u;
    u += 0x7FFFu + ((u >> 16) & 1u);          // round-nearest-even
    return (unsigned short)(u >> 16);
}

// ---- prep: W1 [360][200] f32 -> B-fragment-packed bf16 in ws ----
// layout: bfrag[((kt*NTN + nt)*64 + lane)*8 + e] =
//         bf16(W1[kt*32 + (lane>>4)*8 + e][nt*16 + (lane&15)])  (0 if OOB)
__global__ __launch_bounds__(64) void prep_w1(const float* __restrict__ W1,
                                              unsigned short* __restrict__ bfrag) {
    int blk = blockIdx.x;                 // kt*NTN + nt
    int kt  = blk / NTN, nt = blk % NTN;
    int l   = threadIdx.x;                // 0..63
    int kb  = kt * 32 + (l >> 4) * 8;
    int n   = nt * 16 + (l & 15);
    unsigned short v[8];
    #pragma unroll
    for (int e = 0; e < 8; ++e) {
        int k = kb + e;
        float f = (k < 360 && n < HIDq) ? W1[k * HIDq + n] : 0.f;
        v[e] = f2bf(f);
    }
    bf16x8 pack;
    #pragma unroll
    for (int e = 0; e < 8; ++e) pack[e] = (short)v[e];
    *((bf16x8*)(bfrag + ((size_t)blk * 64 + l) * 8)) = pack;
}

__global__ __launch_bounds__(NTHR) void parser_mfma(
    const float* __restrict__ buffer,
    const unsigned short* __restrict__ bfrag,
    const float* __restrict__ b1,
    const float* __restrict__ W2,
    const float* __restrict__ b2,
    const int*   __restrict__ buffer_index,
    const int*   __restrict__ stack_indexes,
    const int*   __restrict__ stack_len,
    float*       __restrict__ out)
{
    __shared__ unsigned short Afrag[KTN * 64 * 8];  // 12 KiB, A-fragment packed
    __shared__ float hidL[MB][208];                 // 13 KiB
    __shared__ float psum[MB][ONUM][4];
    __shared__ int   sRow[MB][6];
    __shared__ int   sBi[MB], sSl[MB];

    const int t  = threadIdx.x;
    const int s0 = blockIdx.x * MB;

    // ---- indices ----
    if (t < MB) {
        int bi = buffer_index[s0 + t];
        sBi[t] = bi; sSl[t] = stack_len[s0 + t];
        sRow[t][0] = bi; sRow[t][1] = bi + 1; sRow[t][2] = bi + 2;
    }
    if (t < MB * 3) {
        int s = t / 3, c = t % 3;
        sRow[s][3 + c] = stack_indexes[(s0 + s) * 3 + c];
    }
    // zero k-pad region [360,384): kt=11, fragment lanes 16..63
    if (t < 48) {
        f32x4 z = {0.f, 0.f, 0.f, 0.f};
        *((f32x4*)&Afrag[(size_t)(11 * 64 + 16 + t) * 8]) = z;
    }
    __syncthreads();

    // ---- gather X rows, convert to bf16, write in A-fragment layout ----
    // value X[s][k] -> Afrag lane = s + ((k&31)>>3)*16, kt = k>>5, e = k&7
    for (int i = t; i < MB * 90; i += NTHR) {
        int s = i / 90, r = i % 90, seg = r / 15, f = r % 15;
        int row = sRow[s][seg];
        const float4* src = (const float4*)(buffer + ((size_t)(s0 + s) * Lq + row) * Dq);
        float4 v = src[f];
        int k0   = seg * 60 + f * 4;            // k0 % 8 in {0,4}, same kt for 4 vals
        int kt   = k0 >> 5;
        int lane = s + (((k0 & 31) >> 3) << 4);
        ushort4 w;
        w.x = f2bf(v.x); w.y = f2bf(v.y); w.z = f2bf(v.z); w.w = f2bf(v.w);
        *((ushort4*)&Afrag[(size_t)(kt * 64 + lane) * 8 + (k0 & 7)]) = w;
    }
    __syncthreads();

    // ---- layer 1: MFMA over 12 k-tiles; wave w owns n-tiles {w, w+4, w+8[, w+12]} ----
    const int w = t >> 6;
    const int l = t & 63;
    const int nct = (w == 0) ? 4 : 3;
    f32x4 acc[4] = {};
    for (int kt = 0; kt < KTN; ++kt) {
        bf16x8 a = *((const bf16x8*)&Afrag[(size_t)(kt * 64 + l) * 8]);
        #pragma unroll
        for (int i = 0; i < 4; ++i) {
            if (i < nct) {
                int nt = w + 4 * i;
                bf16x8 b = *((const bf16x8*)(bfrag + ((size_t)(kt * NTN + nt) * 64 + l) * 8));
                acc[i] = __builtin_amdgcn_mfma_f32_16x16x32_bf16(a, b, acc[i], 0, 0, 0);
            }
        }
    }

    // ---- bias + ReLU -> hidL ----
    #pragma unroll
    for (int i = 0; i < 4; ++i) {
        if (i < nct) {
            int nt = w + 4 * i;
            int j  = nt * 16 + (l & 15);
            if (j < HIDq) {
                float bb = b1[j];
                #pragma unroll
                for (int r = 0; r < 4; ++r) {
                    int s = ((l >> 4) << 2) + r;     // D row = state
                    float h = acc[i][r] + bb;
                    hidL[s][j] = h > 0.f ? h : 0.f;
                }
            }
        }
    }
    __syncthreads();

    // ---- layer 2: 192 threads, (s,o) x 4-way k-split ----
    if (t < MB * 12) {
        int s = t / 12, rem = t % 12, o = rem >> 2, q = rem & 3;
        const float* hp = &hidL[s][q * 50];
        float a0 = 0.f, a1 = 0.f;
        #pragma unroll 5
        for (int jj = 0; jj < 50; jj += 2) {
            a0 = fmaf(hp[jj],     W2[(q * 50 + jj)     * ONUM + o], a0);
            a1 = fmaf(hp[jj + 1], W2[(q * 50 + jj + 1) * ONUM + o], a1);
        }
        psum[s][o][q] = a0 + a1;
    }
    __syncthreads();

    if (t < MB * ONUM) {
        int s = t / ONUM, o = t % ONUM;
        out[(size_t)(s0 + s) * ONUM + o] =
            psum[s][o][0] + psum[s][o][1] + psum[s][o][2] + psum[s][o][3] + b2[o];
        float lg;
        if (o == 0)      lg = (sBi[s] + 3 >= Lq) ? 0.f : 1.f;
        else if (o == 1) lg = (sSl[s] <= 3)      ? 0.f : 1.f;
        else             lg = (sSl[s] <= 4)      ? 0.f : 1.f;
        out[(size_t)Bq * ONUM + (size_t)(s0 + s) * ONUM + o] = lg;
    }
}

extern "C" void kernel_launch(void* const* d_in, const int* in_sizes, int n_in,
                              void* d_out, int out_size, void* d_ws, size_t ws_size,
                              hipStream_t stream) {
    const float* buffer        = (const float*)d_in[0];
    const float* W1            = (const float*)d_in[1];
    const float* b1            = (const float*)d_in[2];
    const float* W2            = (const float*)d_in[3];
    const float* b2            = (const float*)d_in[4];
    const int*   buffer_index  = (const int*)d_in[5];
    const int*   stack_indexes = (const int*)d_in[6];
    const int*   stack_len     = (const int*)d_in[7];
    float*       out           = (float*)d_out;

    unsigned short* bfrag = (unsigned short*)d_ws;   // 156*64*8*2 = 159,744 B

    prep_w1<<<KTN * NTN, 64, 0, stream>>>(W1, bfrag);
    parser_mfma<<<Bq / MB, NTHR, 0, stream>>>(
        buffer, bfrag, b1, W2, b2, buffer_index, stack_indexes, stack_len, out);
}

// Round 3
// 19.457 us; speedup vs baseline: 1.4128x; 1.1449x over previous
//
#include <hip/hip_runtime.h>

// TBSyntaxParser via bf16 MFMA, v3: 8-wave blocks, in-register layer-2 epilogue.
// B=4096, L=128, D=60, X=360(k, pad 384), HID=200(n, pad 208), OUT=3.
// d_out = [out (B*3) | legal (B*3)] f32.

#define Bq    4096
#define Lq    128
#define Dq    60
#define HIDq  200
#define ONUM  3
#define KTN   12      // k-tiles (384/32)
#define NTN   13      // n-tiles (208/16)
#define MB    16      // states per block (MFMA M)
#define NTHR  512     // 8 waves

typedef short  bf16x8 __attribute__((ext_vector_type(8)));
typedef float  f32x4  __attribute__((ext_vector_type(4)));

__device__ __forceinline__ unsigned short f2bf(float f) {
    union { float f; unsigned int u; } v; v.f = f;
    unsigned int u = v.u;
    u += 0x7FFFu + ((u >> 16) & 1u);          // round-nearest-even
    return (unsigned short)(u >> 16);
}

// ---- prep: W1 [360][200] f32 -> B-fragment-packed bf16 in ws ----
// bfrag[((kt*NTN+nt)*64 + lane)*8 + e] = bf16(W1[kt*32+(lane>>4)*8+e][nt*16+(lane&15)])
__global__ __launch_bounds__(256) void prep_w1(const float* __restrict__ W1,
                                               unsigned short* __restrict__ bfrag) {
    int fid = blockIdx.x * 4 + (threadIdx.x >> 6);   // 39*4 = 156 fragment tiles
    int kt  = fid / NTN, nt = fid % NTN;
    int l   = threadIdx.x & 63;
    int kb  = kt * 32 + (l >> 4) * 8;
    int n   = nt * 16 + (l & 15);
    bf16x8 pack;
    #pragma unroll
    for (int e = 0; e < 8; ++e) {
        int k = kb + e;
        float f = (k < 360 && n < HIDq) ? W1[k * HIDq + n] : 0.f;
        pack[e] = (short)f2bf(f);
    }
    *((bf16x8*)(bfrag + ((size_t)fid * 64 + l) * 8)) = pack;
}

__global__ __launch_bounds__(NTHR) void parser_mfma(
    const float* __restrict__ buffer,
    const unsigned short* __restrict__ bfrag,
    const float* __restrict__ b1,
    const float* __restrict__ W2,
    const float* __restrict__ b2,
    const int*   __restrict__ buffer_index,
    const int*   __restrict__ stack_indexes,
    const int*   __restrict__ stack_len,
    float*       __restrict__ out)
{
    __shared__ unsigned short Afrag[KTN * 64 * 8];   // 12 KiB, A-fragment packed
    __shared__ float psum[8][MB][ONUM];              // 1.5 KiB per-wave partials
    __shared__ int   sRow[MB][6];
    __shared__ int   sBi[MB], sSl[MB];

    const int t  = threadIdx.x;
    const int s0 = blockIdx.x * MB;

    // ---- indices ----
    if (t < MB) {
        int bi = buffer_index[s0 + t];
        sBi[t] = bi; sSl[t] = stack_len[s0 + t];
        sRow[t][0] = bi; sRow[t][1] = bi + 1; sRow[t][2] = bi + 2;
    }
    if (t < MB * 3) {
        int s = t / 3, c = t % 3;
        sRow[s][3 + c] = stack_indexes[(s0 + s) * 3 + c];
    }
    // zero k-pad region of kt=11 (lanes 16..63)
    if (t < 48) {
        f32x4 z = {0.f, 0.f, 0.f, 0.f};
        *((f32x4*)&Afrag[(size_t)(11 * 64 + 16 + t) * 8]) = z;
    }
    __syncthreads();

    // ---- gather X rows -> bf16 A-fragment layout in LDS ----
    // X[s][k] -> kt=k>>5, lane = s + ((k&31)>>3)*16, e = k&7
    for (int i = t; i < MB * 90; i += NTHR) {
        int s = i / 90, r = i % 90, seg = r / 15, f = r % 15;
        int row = sRow[s][seg];
        const float4* src = (const float4*)(buffer + ((size_t)(s0 + s) * Lq + row) * Dq);
        float4 v = src[f];
        int k0   = seg * 60 + f * 4;                 // k0%8 in {0,4}
        int kt   = k0 >> 5;
        int lane = s + (((k0 & 31) >> 3) << 4);
        ushort4 w;
        w.x = f2bf(v.x); w.y = f2bf(v.y); w.z = f2bf(v.z); w.w = f2bf(v.w);
        *((ushort4*)&Afrag[(size_t)(kt * 64 + lane) * 8 + (k0 & 7)]) = w;
    }
    // ---- legal mask (independent of MFMA result) ----
    if (t < MB * ONUM) {
        int s = t / ONUM, o = t % ONUM;
        float lg;
        if (o == 0)      lg = (sBi[s] + 3 >= Lq) ? 0.f : 1.f;
        else if (o == 1) lg = (sSl[s] <= 3)      ? 0.f : 1.f;
        else             lg = (sSl[s] <= 4)      ? 0.f : 1.f;
        out[(size_t)Bq * ONUM + (size_t)(s0 + s) * ONUM + o] = lg;
    }
    __syncthreads();

    // ---- layer 1: wave w owns n-tiles {w, 8+w (if w<5)} ----
    const int w = t >> 6;
    const int l = t & 63;
    const int nt0 = w, nt1 = 8 + w;
    const bool has2 = (w < 5);
    f32x4 acc0 = {}, acc1 = {};
    #pragma unroll
    for (int kt = 0; kt < KTN; ++kt) {
        bf16x8 a  = *((const bf16x8*)&Afrag[(size_t)(kt * 64 + l) * 8]);
        bf16x8 b0 = *((const bf16x8*)(bfrag + ((size_t)(kt * NTN + nt0) * 64 + l) * 8));
        acc0 = __builtin_amdgcn_mfma_f32_16x16x32_bf16(a, b0, acc0, 0, 0, 0);
        if (has2) {
            bf16x8 bB = *((const bf16x8*)(bfrag + ((size_t)(kt * NTN + nt1) * 64 + l) * 8));
            acc1 = __builtin_amdgcn_mfma_f32_16x16x32_bf16(a, bB, acc1, 0, 0, 0);
        }
    }

    // ---- fused epilogue: bias + ReLU + layer-2 partial, all in-register ----
    // lane holds hid_pre[s=(l>>4)*4+r][j=nt*16+(l&15)] in acc[r]
    float p[ONUM][4];
    #pragma unroll
    for (int o = 0; o < ONUM; ++o)
        #pragma unroll
        for (int r = 0; r < 4; ++r) p[o][r] = 0.f;

    {
        int j = nt0 * 16 + (l & 15);                 // nt0<=7 -> j<=127, in range
        float bb = b1[j];
        float w2v0 = W2[j * ONUM + 0], w2v1 = W2[j * ONUM + 1], w2v2 = W2[j * ONUM + 2];
        #pragma unroll
        for (int r = 0; r < 4; ++r) {
            float h = acc0[r] + bb; h = h > 0.f ? h : 0.f;
            p[0][r] = fmaf(h, w2v0, p[0][r]);
            p[1][r] = fmaf(h, w2v1, p[1][r]);
            p[2][r] = fmaf(h, w2v2, p[2][r]);
        }
    }
    if (has2) {
        int j = nt1 * 16 + (l & 15);                 // up to 207: guard >=200
        if (j < HIDq) {
            float bb = b1[j];
            float w2v0 = W2[j * ONUM + 0], w2v1 = W2[j * ONUM + 1], w2v2 = W2[j * ONUM + 2];
            #pragma unroll
            for (int r = 0; r < 4; ++r) {
                float h = acc1[r] + bb; h = h > 0.f ? h : 0.f;
                p[0][r] = fmaf(h, w2v0, p[0][r]);
                p[1][r] = fmaf(h, w2v1, p[1][r]);
                p[2][r] = fmaf(h, w2v2, p[2][r]);
            }
        }
    }

    // butterfly-reduce over the 16-lane column group (j dimension)
    #pragma unroll
    for (int d = 1; d < 16; d <<= 1) {
        #pragma unroll
        for (int o = 0; o < ONUM; ++o)
            #pragma unroll
            for (int r = 0; r < 4; ++r)
                p[o][r] += __shfl_xor(p[o][r], d, 64);
    }
    if ((l & 15) == 0) {
        #pragma unroll
        for (int r = 0; r < 4; ++r) {
            int s = ((l >> 4) << 2) + r;
            #pragma unroll
            for (int o = 0; o < ONUM; ++o) psum[w][s][o] = p[o][r];
        }
    }
    __syncthreads();

    // ---- combine 8 wave-partials + bias, write out ----
    if (t < MB * ONUM) {
        int s = t / ONUM, o = t % ONUM;
        float v = b2[o];
        #pragma unroll
        for (int w8 = 0; w8 < 8; ++w8) v += psum[w8][s][o];
        out[(size_t)(s0 + s) * ONUM + o] = v;
    }
}

extern "C" void kernel_launch(void* const* d_in, const int* in_sizes, int n_in,
                              void* d_out, int out_size, void* d_ws, size_t ws_size,
                              hipStream_t stream) {
    const float* buffer        = (const float*)d_in[0];
    const float* W1            = (const float*)d_in[1];
    const float* b1            = (const float*)d_in[2];
    const float* W2            = (const float*)d_in[3];
    const float* b2            = (const float*)d_in[4];
    const int*   buffer_index  = (const int*)d_in[5];
    const int*   stack_indexes = (const int*)d_in[6];
    const int*   stack_len     = (const int*)d_in[7];
    float*       out           = (float*)d_out;

    unsigned short* bfrag = (unsigned short*)d_ws;   // 156*64*8*2 = 159,744 B

    prep_w1<<<39, 256, 0, stream>>>(W1, bfrag);
    parser_mfma<<<Bq / MB, NTHR, 0, stream>>>(
        buffer, bfrag, b1, W2, b2, buffer_index, stack_indexes, stack_len, out);
}